// Round 4
// baseline (299.165 us; speedup 1.0000x reference)
//
#include <hip/hip_runtime.h>
#include <math.h>

#define BB 4
#define CC 256
#define LL 4096
#define DD 32   // q/k channels
#define LOG2E 1.44269504088896f

typedef __attribute__((ext_vector_type(8))) short short8;   // 8 bf16 (4 VGPRs)
typedef __attribute__((ext_vector_type(4))) short short4v;
typedef __attribute__((ext_vector_type(4))) float f32x4;
typedef __attribute__((ext_vector_type(4))) unsigned int uint4v;

__device__ inline unsigned short f2bf(float f) {
  union { float f; unsigned u; } v; v.f = f;
  unsigned r = v.u + 0x7fffu + ((v.u >> 16) & 1u);  // RNE
  return (unsigned short)(r >> 16);
}

__device__ inline float fast_exp2(float x) {
#if __has_builtin(__builtin_amdgcn_exp2f)
  return __builtin_amdgcn_exp2f(x);   // bare v_exp_f32, no OCML guards
#else
  return exp2f(x);
#endif
}

// position p -> kT storage row within a 32-key group, so that P's MFMA-C layout
// matches the PV B-operand layout with V stored in NATURAL key order.
__device__ __host__ inline int sigma32(int p) {
  const int q4 = (p >> 3) & 3, u = p & 7;
  return 16 * (u >> 2) + 4 * q4 + (u & 3);
}

// ---------------- kernel 0: transpose-cast x -> xT[b][l][c] bf16; W -> bf16 ----------------
// blocks 0..1023: x transpose. blocks 1024..1063: W conversion (2048 elems each).
__global__ __launch_bounds__(256) void prep_kernel(
    const float* __restrict__ x,
    const float* __restrict__ Wq, const float* __restrict__ Wk, const float* __restrict__ Wv,
    unsigned short* __restrict__ xT, unsigned short* __restrict__ Wbf)
{
  const int t = threadIdx.x;
  const int blk = blockIdx.x;
  if (blk >= 1024) {
    int e = (blk - 1024) * 2048 + t;        // 40 blocks cover 81920
    #pragma unroll
    for (int rr = 0; rr < 8; ++rr, e += 256) {
      float v = (e < 8192) ? Wq[e] : (e < 16384) ? Wk[e - 8192] : Wv[e - 16384];
      Wbf[e] = f2bf(v);
    }
    return;
  }
  __shared__ unsigned int T32[64][33];
  const int b  = blk >> 8;
  const int c0 = ((blk >> 6) & 3) * 64;
  const int l0 = (blk & 63) * 64;
  const int l  = t & 63;
  const int cg = t >> 6;
  #pragma unroll
  for (int rr = 0; rr < 8; ++rr) {
    const int c2 = cg * 8 + rr;
    const float* p = x + ((size_t)(b * CC + c0 + 2 * c2)) * LL + l0 + l;
    unsigned lo = f2bf(p[0]);
    unsigned hi = f2bf(p[LL]);
    T32[l][c2] = lo | (hi << 16);
  }
  __syncthreads();
  const int i = t >> 2;
  const int q = t & 3;
  unsigned int r0[8];
  #pragma unroll
  for (int u = 0; u < 8; ++u) r0[u] = T32[i][q * 8 + u];
  unsigned short* dst = xT + ((size_t)b * LL + l0 + i) * CC + c0 + q * 16;
  uint4v v0 = { r0[0], r0[1], r0[2], r0[3] };
  uint4v v1 = { r0[4], r0[5], r0[6], r0[7] };
  *(uint4v*)dst = v0;
  *(uint4v*)(dst + 8) = v1;
}

// ---------------- kernel 1: QKV projection as MFMA GEMM, LDS-staged coalesced stores --------
// M=320 (5 tiles of 64 o-rows), N=4096 (tiles of 128 i), K=256.
// q rows pre-scaled by log2(e); kT rows sigma-permuted; vv natural [b][c][l].
__global__ __launch_bounds__(256) void qkv_kernel(
    const unsigned short* __restrict__ xT, const unsigned short* __restrict__ Wbf,
    const float* __restrict__ bq, const float* __restrict__ bk, const float* __restrict__ bv,
    unsigned short* __restrict__ qT, unsigned short* __restrict__ kT,
    unsigned short* __restrict__ vv)
{
  __shared__ unsigned short stage[9216];
  const int t = threadIdx.x;
  const int w = t >> 6, lane = t & 63, cl = lane & 15, q4 = lane >> 4;
  int blk = blockIdx.x;
  const int Mt = blk % 5; blk /= 5;
  const int it = blk & 31;
  const int b  = blk >> 5;
  const int o0 = Mt * 64;
  const int i0 = it * 128;

  const f32x4 zero = {0.f, 0.f, 0.f, 0.f};
  f32x4 acc[4][2];
  #pragma unroll
  for (int mt = 0; mt < 4; ++mt)
    #pragma unroll
    for (int nt = 0; nt < 2; ++nt) acc[mt][nt] = zero;

  const unsigned short* abase = Wbf + (size_t)(o0 + cl) * CC;
  const unsigned short* bbase = xT + ((size_t)b * LL + i0 + 32 * w + cl) * CC;

  #pragma unroll
  for (int ks = 0; ks < 8; ++ks) {
    const int kof = ks * 32 + q4 * 8;
    short8 a[4], bfr[2];
    #pragma unroll
    for (int mt = 0; mt < 4; ++mt) a[mt] = *(const short8*)(abase + mt * 16 * CC + kof);
    #pragma unroll
    for (int nt = 0; nt < 2; ++nt) bfr[nt] = *(const short8*)(bbase + nt * 16 * CC + kof);
    #pragma unroll
    for (int mt = 0; mt < 4; ++mt)
      #pragma unroll
      for (int nt = 0; nt < 2; ++nt)
        acc[mt][nt] = __builtin_amdgcn_mfma_f32_16x16x32_bf16(a[mt], bfr[nt], acc[mt][nt], 0, 0, 0);
  }

  if (Mt == 0) {
    // ---- q (o<32, scaled by log2 e) + k: stage as [i][o], stride 72 ----
    #pragma unroll
    for (int mt = 0; mt < 4; ++mt) {
      #pragma unroll
      for (int nt = 0; nt < 2; ++nt) {
        const int i = 32 * w + 16 * nt + cl;
        short4v pk;
        #pragma unroll
        for (int r = 0; r < 4; ++r) {
          const int o = 16 * mt + 4 * q4 + r;
          float v = acc[mt][nt][r] + ((o < 32) ? bq[o] : bk[o - 32]);
          if (o < 32) v *= LOG2E;
          pk[r] = (short)f2bf(v);
        }
        *(short4v*)&stage[i * 72 + 16 * mt + 4 * q4] = pk;
      }
    }
    __syncthreads();
    const int i = t >> 1, which = t & 1;
    uint4v d0 = *(const uint4v*)&stage[i * 72 + which * 32];
    uint4v d1 = *(const uint4v*)&stage[i * 72 + which * 32 + 8];
    uint4v d2 = *(const uint4v*)&stage[i * 72 + which * 32 + 16];
    uint4v d3 = *(const uint4v*)&stage[i * 72 + which * 32 + 24];
    const int gi = i0 + i;
    unsigned short* dst;
    if (which == 0) {
      dst = qT + ((size_t)b * LL + gi) * DD;
    } else {
      const int row = (gi & ~31) + sigma32(gi & 31);
      dst = kT + ((size_t)b * LL + row) * DD;
    }
    *(uint4v*)dst = d0; *(uint4v*)(dst + 8) = d1;
    *(uint4v*)(dst + 16) = d2; *(uint4v*)(dst + 24) = d3;
  } else {
    // ---- v (64 rows): stage as [o][i], stride 144 ----
    #pragma unroll
    for (int mt = 0; mt < 4; ++mt)
      #pragma unroll
      for (int nt = 0; nt < 2; ++nt) {
        const int i = 32 * w + 16 * nt + cl;
        #pragma unroll
        for (int r = 0; r < 4; ++r) {
          const int o = 16 * mt + 4 * q4 + r;
          stage[o * 144 + i] = f2bf(acc[mt][nt][r] + bv[o0 - 64 + o]);
        }
      }
    __syncthreads();
    const int ch = t >> 2, part = t & 3;
    uint4v d0 = *(const uint4v*)&stage[ch * 144 + part * 32];
    uint4v d1 = *(const uint4v*)&stage[ch * 144 + part * 32 + 8];
    uint4v d2 = *(const uint4v*)&stage[ch * 144 + part * 32 + 16];
    uint4v d3 = *(const uint4v*)&stage[ch * 144 + part * 32 + 24];
    unsigned short* dst = vv + ((size_t)b * CC + (o0 - 64) + ch) * LL + i0 + part * 32;
    *(uint4v*)dst = d0; *(uint4v*)(dst + 8) = d1;
    *(uint4v*)(dst + 16) = d2; *(uint4v*)(dst + 24) = d3;
  }
}

// ---------------- kernel 2: barrier-free flash attention + residual ----------------
// grid BB*128 blocks (32 queries each), 512 thr = 8 waves: m4 = w&3 (64-ch group),
// kh = w>>2 (2048-key half). Per kstep: S^T = K*Q^T (4 MFMA) -> P in-register
// (v_exp_f32 + v_perm pack) -> PV (8 MFMA) + ones-MFMA. No LDS/barriers in loop.
__global__ __launch_bounds__(512, 4) void attn_kernel(
    const unsigned short* __restrict__ qT, const unsigned short* __restrict__ kT,
    const unsigned short* __restrict__ vv, const float* __restrict__ x,
    const float* __restrict__ gamma_p, float* __restrict__ out)
{
  __shared__ __align__(16) float Omrg[4][8][64][4];   // 32KB epilogue merge
  __shared__ float l_part[2][32];

  const int t = threadIdx.x;
  const int w = t >> 6, lane = t & 63, cl = lane & 15, q4 = lane >> 4;
  const int m4 = w & 3;
  const int kh = w >> 2;
  const int it = blockIdx.x & 127, b = blockIdx.x >> 7;
  const int i0 = it * 32;

  // Q as B-operand: B[k=ch][n=query], one frag per 16-query n-tile
  short8 qa[2];
  #pragma unroll
  for (int nt = 0; nt < 2; ++nt)
    qa[nt] = *(const short8*)(qT + ((size_t)b * LL + i0 + 16 * nt + cl) * DD + q4 * 8);

  short8 ones;
  #pragma unroll
  for (int u = 0; u < 8; ++u) ones[u] = (short)0x3F80;

  const f32x4 zero = {0.f, 0.f, 0.f, 0.f};
  f32x4 O[4][2];
  #pragma unroll
  for (int mt = 0; mt < 4; ++mt)
    #pragma unroll
    for (int nt = 0; nt < 2; ++nt) O[mt][nt] = zero;
  f32x4 lacc = zero;

  const unsigned short* kbase = kT + ((size_t)b * LL + kh * 2048 + cl) * DD + q4 * 8;
  const unsigned short* vbase = vv + ((size_t)b * CC + 64 * m4 + cl) * LL + kh * 2048 + q4 * 8;

  short8 kb[2], va[4], kbn[2], van[4];
  #pragma unroll
  for (int tt = 0; tt < 2; ++tt) kb[tt] = *(const short8*)(kbase + (size_t)(16 * tt) * DD);
  #pragma unroll
  for (int mt = 0; mt < 4; ++mt) va[mt] = *(const short8*)(vbase + (size_t)mt * 16 * LL);

  for (int ks = 0; ks < 64; ++ks) {
    const int nofs = ((ks + 1) & 63) * 32;
    #pragma unroll
    for (int tt = 0; tt < 2; ++tt)
      kbn[tt] = *(const short8*)(kbase + (size_t)(nofs + 16 * tt) * DD);
    #pragma unroll
    for (int mt = 0; mt < 4; ++mt)
      van[mt] = *(const short8*)(vbase + (size_t)mt * 16 * LL + nofs);

    // S^T for 32 queries x 32 keys (storage order)
    f32x4 s0[2], s1[2];
    #pragma unroll
    for (int nt = 0; nt < 2; ++nt) {
      s0[nt] = __builtin_amdgcn_mfma_f32_16x16x32_bf16(kb[0], qa[nt], zero, 0, 0, 0);
      s1[nt] = __builtin_amdgcn_mfma_f32_16x16x32_bf16(kb[1], qa[nt], zero, 0, 0, 0);
    }

    // P = exp2(S^T) packed straight into PV B-frags (hi16 truncation via v_perm)
    union { short8 s; uint4v u; } pb[2];
    #pragma unroll
    for (int nt = 0; nt < 2; ++nt) {
      float e0[4], e1[4];
      #pragma unroll
      for (int r = 0; r < 4; ++r) { e0[r] = fast_exp2(s0[nt][r]); e1[r] = fast_exp2(s1[nt][r]); }
      pb[nt].u.x = __builtin_amdgcn_perm(__float_as_uint(e0[1]), __float_as_uint(e0[0]), 0x07060302);
      pb[nt].u.y = __builtin_amdgcn_perm(__float_as_uint(e0[3]), __float_as_uint(e0[2]), 0x07060302);
      pb[nt].u.z = __builtin_amdgcn_perm(__float_as_uint(e1[1]), __float_as_uint(e1[0]), 0x07060302);
      pb[nt].u.w = __builtin_amdgcn_perm(__float_as_uint(e1[3]), __float_as_uint(e1[2]), 0x07060302);
    }

    // O += V * P   (V natural order thanks to sigma-permuted kT rows)
    #pragma unroll
    for (int mt = 0; mt < 4; ++mt)
      #pragma unroll
      for (int nt = 0; nt < 2; ++nt)
        O[mt][nt] = __builtin_amdgcn_mfma_f32_16x16x32_bf16(va[mt], pb[nt].s, O[mt][nt], 0, 0, 0);
    // l partials: wave m4 covers query group nt=m4 (only m4<2 meaningful/stored)
    lacc = __builtin_amdgcn_mfma_f32_16x16x32_bf16(ones, pb[m4 & 1].s, lacc, 0, 0, 0);

    #pragma unroll
    for (int tt = 0; tt < 2; ++tt) kb[tt] = kbn[tt];
    #pragma unroll
    for (int mt = 0; mt < 4; ++mt) va[mt] = van[mt];
  }

  // ---- epilogue: merge key-halves, normalize, residual ----
  if (m4 < 2 && lane < 16) l_part[kh][16 * m4 + lane] = lacc[0];
  if (kh == 1) {
    #pragma unroll
    for (int mt = 0; mt < 4; ++mt)
      #pragma unroll
      for (int nt = 0; nt < 2; ++nt)
        *(f32x4*)&Omrg[m4][mt * 2 + nt][lane][0] = O[mt][nt];
  }
  __syncthreads();
  if (kh == 0) {
    const float gam = gamma_p[0];
    float inv_l[2];
    #pragma unroll
    for (int nt = 0; nt < 2; ++nt)
      inv_l[nt] = 1.0f / (l_part[0][16 * nt + cl] + l_part[1][16 * nt + cl]);
    #pragma unroll
    for (int mt = 0; mt < 4; ++mt) {
      #pragma unroll
      for (int nt = 0; nt < 2; ++nt) {
        const f32x4 om = *(const f32x4*)&Omrg[m4][mt * 2 + nt][lane][0];
        #pragma unroll
        for (int r = 0; r < 4; ++r) {
          const int ch = 64 * m4 + 16 * mt + 4 * q4 + r;
          const int i  = i0 + 16 * nt + cl;
          const size_t idx = ((size_t)b * CC + ch) * LL + i;
          out[idx] = gam * (O[mt][nt][r] + om[r]) * inv_l[nt] + x[idx];
        }
      }
    }
  }
}

extern "C" void kernel_launch(void* const* d_in, const int* in_sizes, int n_in,
                              void* d_out, int out_size, void* d_ws, size_t ws_size,
                              hipStream_t stream) {
  const float* x     = (const float*)d_in[0];
  const float* Wq    = (const float*)d_in[1];
  const float* bq    = (const float*)d_in[2];
  const float* Wk    = (const float*)d_in[3];
  const float* bk    = (const float*)d_in[4];
  const float* Wv    = (const float*)d_in[5];
  const float* bv    = (const float*)d_in[6];
  const float* gamma = (const float*)d_in[7];
  float* out = (float*)d_out;

  // d_out doubles as scratch until attn_kernel's final full overwrite:
  unsigned short* xT  = (unsigned short*)d_out;            // 8MB
  unsigned short* Wbf = xT + (size_t)BB * LL * CC;         // 160KB

  // ws: qT (1MB, pre-scaled by log2 e) | kT (1MB, sigma-permuted rows) | vv (8MB, natural)
  unsigned short* qT = (unsigned short*)d_ws;
  unsigned short* kT = qT + (size_t)BB * LL * DD;
  unsigned short* vv = kT + (size_t)BB * LL * DD;

  prep_kernel<<<1064, 256, 0, stream>>>(x, Wq, Wk, Wv, xT, Wbf);
  qkv_kernel<<<5 * 32 * BB, 256, 0, stream>>>(xT, Wbf, bq, bk, bv, qT, kT, vv);
  attn_kernel<<<BB * 128, 512, 0, stream>>>(qT, kT, vv, x, gamma, out);
}

// Round 5
// 219.633 us; speedup vs baseline: 1.3621x; 1.3621x over previous
//
#include <hip/hip_runtime.h>
#include <math.h>

#define BB 4
#define CC 256
#define LL 4096
#define DD 32   // q/k channels
#define LOG2E 1.44269504088896f

typedef __attribute__((ext_vector_type(8))) short short8;   // 8 bf16 (4 VGPRs)
typedef __attribute__((ext_vector_type(4))) short short4v;
typedef __attribute__((ext_vector_type(4))) float f32x4;
typedef __attribute__((ext_vector_type(4))) unsigned int uint4v;

__device__ inline unsigned short f2bf(float f) {
  union { float f; unsigned u; } v; v.f = f;
  unsigned r = v.u + 0x7fffu + ((v.u >> 16) & 1u);  // RNE
  return (unsigned short)(r >> 16);
}

__device__ inline float fast_exp2(float x) {
#if __has_builtin(__builtin_amdgcn_exp2f)
  return __builtin_amdgcn_exp2f(x);   // bare v_exp_f32
#else
  return exp2f(x);
#endif
}

// natural key p -> kT storage row within its 32-key group; makes P's MFMA-C
// layout coincide with the PV B-operand layout for V in natural key order.
__device__ __host__ inline int sigma32(int p) {
  const int q4 = (p >> 3) & 3, u = p & 7;
  return 16 * (u >> 2) + 4 * q4 + (u & 3);
}

// ---------------- kernel 0: W -> bf16 MFMA-fragment-linear layout ----------------
// wf[ot(20)][ks(8)][lane(64)][8] ; A-frag A[m=o16][k=c32]: lane(cl,q4) j -> W[ot*16+cl][ks*32+q4*8+j]
// Wq rows pre-scaled by log2(e) (folds softmax exp2 conversion).
__global__ __launch_bounds__(256) void wprep_kernel(
    const float* __restrict__ Wq, const float* __restrict__ Wk, const float* __restrict__ Wv,
    unsigned short* __restrict__ wf)
{
  const int t = threadIdx.x;
  const int ot = blockIdx.x >> 1;           // 0..19
  const int rep = blockIdx.x & 1;
  const int lane = t & 63, cl = lane & 15, q4 = lane >> 4;
  const int ks = (t >> 6) + 4 * rep;        // 0..7
  const int o = ot * 16 + cl;
  const int c = ks * 32 + q4 * 8;
  const float* src = (o < 32) ? (Wq + o * CC) : (o < 64) ? (Wk + (o - 32) * CC)
                                              : (Wv + (o - 64) * CC);
  const float sc = (o < 32) ? LOG2E : 1.0f;
  unsigned short p[8];
  #pragma unroll
  for (int j = 0; j < 8; ++j) p[j] = f2bf(src[c + j] * sc);
  uint4v u;
  u.x = (unsigned)p[0] | ((unsigned)p[1] << 16);
  u.y = (unsigned)p[2] | ((unsigned)p[3] << 16);
  u.z = (unsigned)p[4] | ((unsigned)p[5] << 16);
  u.w = (unsigned)p[6] | ((unsigned)p[7] << 16);
  *(uint4v*)(wf + ((size_t)(ot * 8 + ks) * 64 + lane) * 8) = u;
}

// ---------------- kernel 1: fused transpose + QKV projection ----------------
// grid 256 = (b, jt 64-key tile) XCD-affine; 256 thr, 4 waves.
// Stage x[b][0..255][i0..i0+63] into LDS (transposed, fp32, pad-261), then
// wave w computes all 320 o-rows for its 16 i-columns. Outputs staged in LDS
// and stored coalesced: qT rows, kT sigma rows, vf fragment-linear.
__global__ __launch_bounds__(256, 2) void qkv_kernel(
    const float* __restrict__ x, const unsigned short* __restrict__ wf,
    const float* __restrict__ bq, const float* __restrict__ bk, const float* __restrict__ bv,
    unsigned short* __restrict__ qT, unsigned short* __restrict__ kT,
    unsigned short* __restrict__ vf)
{
  __shared__ union {
    float xl[64 * 261];                                   // [i][c] pad-261
    struct {
      unsigned short qk[64 * 72];                         // [i][o 0..63]
      __align__(16) unsigned short v[256 * 88];           // [ch][key] pad-88
    } ep;
  } sm;

  const int t = threadIdx.x;
  const int w = t >> 6, lane = t & 63, cl = lane & 15, q4 = lane >> 4;
  const int blk = blockIdx.x;
  const int x3 = blk & 7;
  const int b  = x3 >> 1;                                 // XCD-batch affinity
  const int jt = (blk >> 3) * 2 + (x3 & 1);
  const int i0 = jt * 64;

  // ---- stage: coalesced 256B-row loads, transposed scatter into LDS ----
  {
    const int sub = lane >> 4;       // row within 4-row instr
    const int ic  = lane & 15;       // 16B i-chunk
    for (int r = 0; r < 16; ++r) {
      const int c = 64 * w + 4 * r + sub;
      const f32x4 v = *(const f32x4*)(x + ((size_t)(b * CC + c)) * LL + i0 + ic * 4);
      #pragma unroll
      for (int k = 0; k < 4; ++k) sm.xl[(ic * 4 + k) * 261 + c] = v[k];
    }
  }
  __syncthreads();

  // ---- GEMM: 320 o x 16 i (this wave) x 256 c ----
  const f32x4 zero = {0.f, 0.f, 0.f, 0.f};
  f32x4 acc[20];
  #pragma unroll
  for (int ot = 0; ot < 20; ++ot) acc[ot] = zero;

  for (int ks = 0; ks < 8; ++ks) {
    unsigned short p[8];
    #pragma unroll
    for (int j = 0; j < 8; ++j)
      p[j] = f2bf(sm.xl[(16 * w + cl) * 261 + ks * 32 + q4 * 8 + j]);
    union { short8 s; uint4v u; } bfr;
    bfr.u.x = (unsigned)p[0] | ((unsigned)p[1] << 16);
    bfr.u.y = (unsigned)p[2] | ((unsigned)p[3] << 16);
    bfr.u.z = (unsigned)p[4] | ((unsigned)p[5] << 16);
    bfr.u.w = (unsigned)p[6] | ((unsigned)p[7] << 16);
    #pragma unroll
    for (int ot = 0; ot < 20; ++ot) {
      const short8 a = *(const short8*)(wf + ((size_t)(ot * 8 + ks) * 64 + lane) * 8);
      acc[ot] = __builtin_amdgcn_mfma_f32_16x16x32_bf16(a, bfr.s, acc[ot], 0, 0, 0);
    }
  }
  __syncthreads();   // xl dead; alias as ep stages

  // ---- stage outputs: q/k as [i][o], v as [ch][key] ----
  #pragma unroll
  for (int ot = 0; ot < 4; ++ot) {
    short4v pk;
    #pragma unroll
    for (int r = 0; r < 4; ++r) {
      const int o = 16 * ot + 4 * q4 + r;
      const float v = acc[ot][r] + ((o < 32) ? bq[o] * LOG2E : bk[o - 32]);
      pk[r] = (short)f2bf(v);
    }
    *(short4v*)&sm.ep.qk[(16 * w + cl) * 72 + 16 * ot + 4 * q4] = pk;
  }
  #pragma unroll
  for (int ot = 4; ot < 20; ++ot) {
    #pragma unroll
    for (int r = 0; r < 4; ++r) {
      const int ch = 16 * (ot - 4) + 4 * q4 + r;
      sm.ep.v[ch * 88 + 16 * w + cl] = f2bf(acc[ot][r] + bv[ch]);
    }
  }
  __syncthreads();

  // ---- coalesced global stores ----
  if (t < 128) {
    const int i = t >> 1, which = t & 1;
    const int gi = i0 + i;
    const unsigned short* srcp = &sm.ep.qk[i * 72 + which * 32];
    uint4v d0 = *(const uint4v*)(srcp + 0);
    uint4v d1 = *(const uint4v*)(srcp + 8);
    uint4v d2 = *(const uint4v*)(srcp + 16);
    uint4v d3 = *(const uint4v*)(srcp + 24);
    unsigned short* dst;
    if (which == 0) {
      dst = qT + ((size_t)b * LL + gi) * DD;
    } else {
      const int row = (gi & ~31) + sigma32(gi & 31);
      dst = kT + ((size_t)b * LL + row) * DD;
    }
    *(uint4v*)dst = d0; *(uint4v*)(dst + 8) = d1;
    *(uint4v*)(dst + 16) = d2; *(uint4v*)(dst + 24) = d3;
  }
  // vf: 32 frags x 1KB, fragment-linear: f = (m4*2+kk)*4+mt
  #pragma unroll
  for (int rep = 0; rep < 8; ++rep) {
    const int slot = t + 256 * rep;
    const int f = slot >> 6, l2 = slot & 63;
    const int cl2 = l2 & 15, q42 = l2 >> 4;
    const int m4 = f >> 3, kk = (f >> 2) & 1, mt = f & 3;
    const int ch = 64 * m4 + 16 * mt + cl2;
    const int key = kk * 32 + q42 * 8;
    const uint4v dv = *(const uint4v*)&sm.ep.v[ch * 88 + key];
    *(uint4v*)(vf + (((size_t)(b * 64 + jt) * 32 + f) * 64 + l2) * 8) = dv;
  }
}

// ---------------- kernel 2: barrier-free flash attention + residual ----------------
// grid 256 = (b, it 64-query tile) XCD-affine; 512 thr = 8 waves (m4 ch-group, kh key-half).
// Per kstep: S^T = K Q^T (8 MFMA) -> P in-register (v_exp + v_perm) -> PV (16 MFMA) + ones.
// All global loads are single-request contiguous 1KB fragments. No LDS/barriers in loop.
__global__ __launch_bounds__(512, 2) void attn_kernel(
    const unsigned short* __restrict__ qT, const unsigned short* __restrict__ kT,
    const unsigned short* __restrict__ vf, const float* __restrict__ x,
    const float* __restrict__ gamma_p, float* __restrict__ out)
{
  __shared__ __align__(16) float Omrg[4][16][64][4];   // 64KB epilogue merge
  __shared__ float l_part[2][64];

  const int t = threadIdx.x;
  const int w = t >> 6, lane = t & 63, cl = lane & 15, q4 = lane >> 4;
  const int m4 = w & 3, kh = w >> 2;
  const int blk = blockIdx.x;
  const int x3 = blk & 7;
  const int b  = x3 >> 1;                               // matches qkv affinity
  const int it = (blk >> 3) * 2 + (x3 & 1);
  const int i0 = it * 64;

  short8 qa[4];
  #pragma unroll
  for (int nt = 0; nt < 4; ++nt)
    qa[nt] = *(const short8*)(qT + ((size_t)b * LL + i0 + 16 * nt + cl) * DD + q4 * 8);

  short8 ones;
  #pragma unroll
  for (int u = 0; u < 8; ++u) ones[u] = (short)0x3F80;

  const f32x4 zero = {0.f, 0.f, 0.f, 0.f};
  f32x4 O[4][4];
  #pragma unroll
  for (int mt = 0; mt < 4; ++mt)
    #pragma unroll
    for (int nt = 0; nt < 4; ++nt) O[mt][nt] = zero;
  f32x4 lacc = zero;

  const unsigned short* kbase = kT + ((size_t)b * LL + kh * 32 + cl) * DD + q4 * 8;
  const unsigned short* vbase = vf + ((size_t)(b * 64) * 32 + (m4 * 2 + kh) * 4) * 512 + lane * 8;

  short8 kb[2], va[4], kbn[2], van[4];
  #pragma unroll
  for (int tt = 0; tt < 2; ++tt) kb[tt] = *(const short8*)(kbase + (size_t)(16 * tt) * DD);
  #pragma unroll
  for (int mt = 0; mt < 4; ++mt) va[mt] = *(const short8*)(vbase + mt * 512);

  for (int ks = 0; ks < 64; ++ks) {
    const int kn = (ks + 1) & 63;
    #pragma unroll
    for (int tt = 0; tt < 2; ++tt)
      kbn[tt] = *(const short8*)(kbase + (size_t)(kn * 64 + 16 * tt) * DD);
    #pragma unroll
    for (int mt = 0; mt < 4; ++mt)
      van[mt] = *(const short8*)(vbase + (size_t)kn * 16384 + mt * 512);

    // S^T: this wave's 32-key half x 64 queries
    f32x4 s0[4], s1[4];
    #pragma unroll
    for (int nt = 0; nt < 4; ++nt) {
      s0[nt] = __builtin_amdgcn_mfma_f32_16x16x32_bf16(kb[0], qa[nt], zero, 0, 0, 0);
      s1[nt] = __builtin_amdgcn_mfma_f32_16x16x32_bf16(kb[1], qa[nt], zero, 0, 0, 0);
    }

    // P = exp2(S^T) packed into PV B-frags (hi16 truncation via v_perm)
    union { short8 s; uint4v u; } pb[4];
    #pragma unroll
    for (int nt = 0; nt < 4; ++nt) {
      float e0[4], e1[4];
      #pragma unroll
      for (int r = 0; r < 4; ++r) { e0[r] = fast_exp2(s0[nt][r]); e1[r] = fast_exp2(s1[nt][r]); }
      pb[nt].u.x = __builtin_amdgcn_perm(__float_as_uint(e0[1]), __float_as_uint(e0[0]), 0x07060302);
      pb[nt].u.y = __builtin_amdgcn_perm(__float_as_uint(e0[3]), __float_as_uint(e0[2]), 0x07060302);
      pb[nt].u.z = __builtin_amdgcn_perm(__float_as_uint(e1[1]), __float_as_uint(e1[0]), 0x07060302);
      pb[nt].u.w = __builtin_amdgcn_perm(__float_as_uint(e1[3]), __float_as_uint(e1[2]), 0x07060302);
    }

    // O += V * P over this wave's 32 keys
    #pragma unroll
    for (int mt = 0; mt < 4; ++mt)
      #pragma unroll
      for (int nt = 0; nt < 4; ++nt)
        O[mt][nt] = __builtin_amdgcn_mfma_f32_16x16x32_bf16(va[mt], pb[nt].s, O[mt][nt], 0, 0, 0);
    // l partial: wave m4 covers query tile nt=m4
    lacc = __builtin_amdgcn_mfma_f32_16x16x32_bf16(ones, pb[m4].s, lacc, 0, 0, 0);

    #pragma unroll
    for (int tt = 0; tt < 2; ++tt) kb[tt] = kbn[tt];
    #pragma unroll
    for (int mt = 0; mt < 4; ++mt) va[mt] = van[mt];
  }

  // ---- epilogue: merge key-halves, normalize, residual ----
  if (lane < 16) l_part[kh][16 * m4 + lane] = lacc[0];
  if (kh == 1) {
    #pragma unroll
    for (int mt = 0; mt < 4; ++mt)
      #pragma unroll
      for (int nt = 0; nt < 4; ++nt)
        *(f32x4*)&Omrg[m4][mt * 4 + nt][lane][0] = O[mt][nt];
  }
  __syncthreads();
  if (kh == 0) {
    const float gam = gamma_p[0];
    float inv_l[4];
    #pragma unroll
    for (int nt = 0; nt < 4; ++nt)
      inv_l[nt] = 1.0f / (l_part[0][16 * nt + cl] + l_part[1][16 * nt + cl]);
    #pragma unroll
    for (int mt = 0; mt < 4; ++mt) {
      #pragma unroll
      for (int nt = 0; nt < 4; ++nt) {
        const f32x4 om = *(const f32x4*)&Omrg[m4][mt * 4 + nt][lane][0];
        #pragma unroll
        for (int r = 0; r < 4; ++r) {
          const int ch = 64 * m4 + 16 * mt + 4 * q4 + r;
          const int i  = i0 + 16 * nt + cl;
          const size_t idx = ((size_t)b * CC + ch) * LL + i;
          out[idx] = gam * (O[mt][nt][r] + om[r]) * inv_l[nt] + x[idx];
        }
      }
    }
  }
}

extern "C" void kernel_launch(void* const* d_in, const int* in_sizes, int n_in,
                              void* d_out, int out_size, void* d_ws, size_t ws_size,
                              hipStream_t stream) {
  const float* x     = (const float*)d_in[0];
  const float* Wq    = (const float*)d_in[1];
  const float* bq    = (const float*)d_in[2];
  const float* Wk    = (const float*)d_in[3];
  const float* bk    = (const float*)d_in[4];
  const float* Wv    = (const float*)d_in[5];
  const float* bv    = (const float*)d_in[6];
  const float* gamma = (const float*)d_in[7];
  float* out = (float*)d_out;

  // ws: qT (1MB, log2e-scaled) | kT (1MB, sigma rows) | vf (8MB, fragment-linear)
  unsigned short* qT = (unsigned short*)d_ws;
  unsigned short* kT = qT + (size_t)BB * LL * DD;
  unsigned short* vf = kT + (size_t)BB * LL * DD;
  // wf (160KB) lives in d_out; consumed by qkv, then attn overwrites d_out
  unsigned short* wf = (unsigned short*)d_out;

  wprep_kernel<<<40, 256, 0, stream>>>(Wq, Wk, Wv, wf);
  qkv_kernel<<<256, 256, 0, stream>>>(x, wf, bq, bk, bv, qT, kT, vf);
  attn_kernel<<<256, 512, 0, stream>>>(qT, kT, vf, x, gamma, out);
}

// Round 6
// 171.877 us; speedup vs baseline: 1.7406x; 1.2779x over previous
//
#include <hip/hip_runtime.h>
#include <math.h>

#define BB 4
#define CC 256
#define LL 4096
#define DD 32   // q/k channels
#define LOG2E 1.44269504088896f

typedef __attribute__((ext_vector_type(8))) short short8;   // 8 bf16 (4 VGPRs)
typedef __attribute__((ext_vector_type(4))) short short4v;
typedef __attribute__((ext_vector_type(4))) float f32x4;
typedef __attribute__((ext_vector_type(4))) unsigned int uint4v;
typedef __attribute__((ext_vector_type(2))) unsigned int uint2v;

// raw workgroup barrier: waits LDS ops only — global prefetches stay in flight
#define BARRIER() asm volatile("s_waitcnt lgkmcnt(0)\n\ts_barrier" ::: "memory")

__device__ inline unsigned short f2bf(float f) {
  union { float f; unsigned u; } v; v.f = f;
  unsigned r = v.u + 0x7fffu + ((v.u >> 16) & 1u);  // RNE
  return (unsigned short)(r >> 16);
}

__device__ inline float fast_exp2(float x) {
#if __has_builtin(__builtin_amdgcn_exp2f)
  return __builtin_amdgcn_exp2f(x);
#else
  return exp2f(x);
#endif
}

// natural key p -> kT storage row within its 32-key group (P C-layout == PV B-layout)
__device__ __host__ inline int sigma32(int p) {
  const int q4 = (p >> 3) & 3, u = p & 7;
  return 16 * (u >> 2) + 4 * q4 + (u & 3);
}

// ---------------- kernel 0: W -> bf16 MFMA-fragment-linear layout ----------------
// wf[ot(20)][ks(8)][lane(64)][8]; Wq rows pre-scaled by log2(e).
__global__ __launch_bounds__(256) void wprep_kernel(
    const float* __restrict__ Wq, const float* __restrict__ Wk, const float* __restrict__ Wv,
    unsigned short* __restrict__ wf)
{
  const int t = threadIdx.x;
  const int ot = blockIdx.x >> 1;           // 0..19
  const int rep = blockIdx.x & 1;
  const int lane = t & 63, cl = lane & 15, q4 = lane >> 4;
  const int ks = (t >> 6) + 4 * rep;        // 0..7
  const int o = ot * 16 + cl;
  const int c = ks * 32 + q4 * 8;
  const float* src = (o < 32) ? (Wq + o * CC) : (o < 64) ? (Wk + (o - 32) * CC)
                                              : (Wv + (o - 64) * CC);
  const float sc = (o < 32) ? LOG2E : 1.0f;
  unsigned short p[8];
  #pragma unroll
  for (int j = 0; j < 8; ++j) p[j] = f2bf(src[c + j] * sc);
  uint4v u;
  u.x = (unsigned)p[0] | ((unsigned)p[1] << 16);
  u.y = (unsigned)p[2] | ((unsigned)p[3] << 16);
  u.z = (unsigned)p[4] | ((unsigned)p[5] << 16);
  u.w = (unsigned)p[6] | ((unsigned)p[7] << 16);
  *(uint4v*)(wf + ((size_t)(ot * 8 + ks) * 64 + lane) * 8) = u;
}

// ---------------- kernel 1: fused transpose + QKV projection ----------------
// grid 512 = (b, it 32-i tile) XCD-affine; 512 thr = 8 waves (wi 16-i, wo 5-ot).
__global__ __launch_bounds__(512, 4) void qkv_kernel(
    const float* __restrict__ x, const unsigned short* __restrict__ wf,
    const float* __restrict__ bq, const float* __restrict__ bk, const float* __restrict__ bv,
    unsigned short* __restrict__ qT, unsigned short* __restrict__ kT,
    unsigned short* __restrict__ vf)
{
  __shared__ union {
    float xl[32 * 261];                                   // [i][c] odd stride
    struct {
      unsigned short qk[32 * 72];                         // [i][o 0..63]
      __align__(16) unsigned short v[256 * 40];           // [ch][key 0..31] pad-40
    } ep;
  } sm;

  const int t = threadIdx.x;
  const int lane = t & 63, cl = lane & 15, q4 = lane >> 4;
  const int blk = blockIdx.x;
  const int b  = (blk & 7) >> 1;                          // XCD-batch affinity
  const int it = ((blk >> 3) << 1) + (blk & 1);           // 0..127
  const int i0 = it * 32;

  // ---- stage x: coalesced 128B rows -> LDS transposed ----
  {
    const int ln8 = t & 7;
    #pragma unroll
    for (int p = 0; p < 4; ++p) {
      const int c = (t >> 3) + 64 * p;
      const f32x4 v = *(const f32x4*)(x + ((size_t)(b * CC + c)) * LL + i0 + ln8 * 4);
      #pragma unroll
      for (int k = 0; k < 4; ++k) sm.xl[(ln8 * 4 + k) * 261 + c] = v[k];
    }
  }
  __syncthreads();

  // ---- GEMM: wave (wi,wo): 80 o-rows x 16 i x 256 c ----
  const int wi = (t >> 6) & 1, wo = t >> 7;
  const f32x4 zero = {0.f, 0.f, 0.f, 0.f};
  f32x4 acc[5];
  #pragma unroll
  for (int u = 0; u < 5; ++u) acc[u] = zero;

  for (int ks = 0; ks < 8; ++ks) {
    unsigned short p[8];
    #pragma unroll
    for (int j = 0; j < 8; ++j)
      p[j] = f2bf(sm.xl[(16 * wi + cl) * 261 + ks * 32 + q4 * 8 + j]);
    union { short8 s; uint4v u; } bfr;
    bfr.u.x = (unsigned)p[0] | ((unsigned)p[1] << 16);
    bfr.u.y = (unsigned)p[2] | ((unsigned)p[3] << 16);
    bfr.u.z = (unsigned)p[4] | ((unsigned)p[5] << 16);
    bfr.u.w = (unsigned)p[6] | ((unsigned)p[7] << 16);
    #pragma unroll
    for (int u = 0; u < 5; ++u) {
      const short8 a = *(const short8*)(wf + ((size_t)((wo * 5 + u) * 8 + ks) * 64 + lane) * 8);
      acc[u] = __builtin_amdgcn_mfma_f32_16x16x32_bf16(a, bfr.s, acc[u], 0, 0, 0);
    }
  }
  __syncthreads();   // xl dead; alias as ep

  // ---- stage outputs ----
  #pragma unroll
  for (int u = 0; u < 5; ++u) {
    const int g = wo * 5 + u;
    if (g < 4) {     // q (g<2) / k
      short4v pk;
      #pragma unroll
      for (int r = 0; r < 4; ++r) {
        const int o = 16 * g + 4 * q4 + r;
        const float v = acc[u][r] + ((o < 32) ? bq[o] * LOG2E : bk[o - 32]);
        pk[r] = (short)f2bf(v);
      }
      *(short4v*)&sm.ep.qk[(16 * wi + cl) * 72 + 16 * g + 4 * q4] = pk;
    } else {
      #pragma unroll
      for (int r = 0; r < 4; ++r) {
        const int ch = 16 * (g - 4) + 4 * q4 + r;
        sm.ep.v[ch * 40 + 16 * wi + cl] = f2bf(acc[u][r] + bv[ch]);
      }
    }
  }
  __syncthreads();

  // ---- coalesced stores ----
  if (t < 64) {
    const int i = t >> 1, which = t & 1;
    const int gi = i0 + i;
    const unsigned short* srcp = &sm.ep.qk[i * 72 + which * 32];
    uint4v d0 = *(const uint4v*)(srcp + 0);
    uint4v d1 = *(const uint4v*)(srcp + 8);
    uint4v d2 = *(const uint4v*)(srcp + 16);
    uint4v d3 = *(const uint4v*)(srcp + 24);
    unsigned short* dst;
    if (which == 0) {
      dst = qT + ((size_t)b * LL + gi) * DD;
    } else {
      const int row = (gi & ~31) + sigma32(gi & 31);
      dst = kT + ((size_t)b * LL + row) * DD;
    }
    *(uint4v*)dst = d0; *(uint4v*)(dst + 8) = d1;
    *(uint4v*)(dst + 16) = d2; *(uint4v*)(dst + 24) = d3;
  }
  // vf: this block covers kk = it&1 of jt = it>>1: 16 frags x 1KB
  const int kk = it & 1, jt = it >> 1;
  #pragma unroll
  for (int rep = 0; rep < 2; ++rep) {
    const int slot = t + 512 * rep;
    const int fl = slot >> 6, l2 = slot & 63;
    const int cl2 = l2 & 15, q42 = l2 >> 4;
    const int m4 = fl >> 2, mt = fl & 3;
    const int fg = 8 * m4 + 4 * kk + mt;
    const int ch = 64 * m4 + 16 * mt + cl2;
    const uint4v d = *(const uint4v*)&sm.ep.v[ch * 40 + q42 * 8];
    *(uint4v*)(vf + (((size_t)(b * 64 + jt)) * 32 + fg) * 512 + l2 * 8) = d;
  }
}

// ---------------- kernel 2: flash attention, LDS-shared P, raw barriers ----------------
// grid 256 = (b, it 64-q tile); 1024 thr = 16 waves.
// Superstep = 256 keys. Phase A: wave w computes S/exp for 16-key slice w -> P LDS (dbuf).
// Phase B: wave (m8=w>>1: 32ch, kh=w&1: 128-key half) PV from LDS P + 1KB va frags.
// One raw s_barrier (lgkm only) per superstep; global prefetches live across it.
__global__ __launch_bounds__(1024, 4) void attn_kernel(
    const unsigned short* __restrict__ qT, const unsigned short* __restrict__ kT,
    const unsigned short* __restrict__ vf, const float* __restrict__ x,
    const float* __restrict__ gamma_p, float* __restrict__ out)
{
  __shared__ union {
    unsigned short P[2][8][4][64][8];   // [buf][kk][nt][lane][j]  64 KB
    float Om[8][8][64][4];              // epilogue merge           64 KB
  } sm;
  __shared__ float l_buf[16][64];

  const int t = threadIdx.x;
  const int w = t >> 6, lane = t & 63, cl = lane & 15, q4 = lane >> 4;
  const int m8 = w >> 1, kh = w & 1;
  const int blk = blockIdx.x;
  const int b  = (blk & 7) >> 1;
  const int it = ((blk >> 3) << 1) + (blk & 1);           // 0..63
  const int i0 = it * 64;

  // persistent Q B-frags (one per 16-query tile)
  short8 qa[4];
  #pragma unroll
  for (int nt = 0; nt < 4; ++nt)
    qa[nt] = *(const short8*)(qT + ((size_t)b * LL + i0 + 16 * nt + cl) * DD + q4 * 8);

  const f32x4 zero = {0.f, 0.f, 0.f, 0.f};
  f32x4 O[2][4];
  #pragma unroll
  for (int mtp = 0; mtp < 2; ++mtp)
    #pragma unroll
    for (int nt = 0; nt < 4; ++nt) O[mtp][nt] = zero;
  float l_r[4] = {0.f, 0.f, 0.f, 0.f};

  const unsigned short* kbase = kT + ((size_t)b * LL + 16 * w + cl) * DD + q4 * 8;
  const unsigned short* vroot = vf + ((size_t)(b * 64)) * 32 * 512 + lane * 8;
  // va address for (ss, e): kk = kh*4+e; jt = ss*4 + (kk>>1); fg = 8*(m8>>1) + 4*(kk&1) + 2*(m8&1)+mtp
  const int mtg = 2 * (m8 & 1), m4b = 8 * (m8 >> 1);

  short8 kb = *(const short8*)kbase;
  short8 va[2][2];
  #pragma unroll
  for (int e = 0; e < 2; ++e) {
    const int kk = kh * 4 + e;
    const int fg = m4b + 4 * (kk & 1) + mtg;
    #pragma unroll
    for (int mtp = 0; mtp < 2; ++mtp)
      va[e][mtp] = *(const short8*)(vroot + ((size_t)((kk >> 1) * 32) + fg + mtp) * 512);
  }

  for (int ss = 0; ss < 16; ++ss) {
    const int buf = ss & 1;

    // ---- phase A: S for this wave's 16-key slice ----
    f32x4 s[4];
    #pragma unroll
    for (int nt = 0; nt < 4; ++nt)
      s[nt] = __builtin_amdgcn_mfma_f32_16x16x32_bf16(kb, qa[nt], zero, 0, 0, 0);
    // prefetch next superstep's kb (in flight across barrier)
    kb = *(const short8*)(kbase + (size_t)((ss + 1) & 15) * 256 * DD);

    #pragma unroll
    for (int nt = 0; nt < 4; ++nt) {
      const float e0 = fast_exp2(s[nt][0]);
      const float e1 = fast_exp2(s[nt][1]);
      const float e2 = fast_exp2(s[nt][2]);
      const float e3 = fast_exp2(s[nt][3]);
      uint2v uv;
      uv.x = __builtin_amdgcn_perm(__float_as_uint(e1), __float_as_uint(e0), 0x07060302);
      uv.y = __builtin_amdgcn_perm(__float_as_uint(e3), __float_as_uint(e2), 0x07060302);
      *(uint2v*)&sm.P[buf][w >> 1][nt][lane][(w & 1) * 4] = uv;
      float sum = (e0 + e1) + (e2 + e3);
      sum += __shfl_xor(sum, 16);
      sum += __shfl_xor(sum, 32);
      l_r[nt] += sum;
    }
    BARRIER();

    // ---- phase B: PV over this wave's 128-key half ----
    #pragma unroll
    for (int e = 0; e < 4; ++e) {
      const int kk = kh * 4 + e;
      short8 pb[4];
      #pragma unroll
      for (int nt = 0; nt < 4; ++nt)
        pb[nt] = *(const short8*)&sm.P[buf][kk][nt][lane][0];
      #pragma unroll
      for (int nt = 0; nt < 4; ++nt) {
        O[0][nt] = __builtin_amdgcn_mfma_f32_16x16x32_bf16(va[e & 1][0], pb[nt], O[0][nt], 0, 0, 0);
        O[1][nt] = __builtin_amdgcn_mfma_f32_16x16x32_bf16(va[e & 1][1], pb[nt], O[1][nt], 0, 0, 0);
      }
      // refill the consumed slot: e<2 -> (ss, kk+2); else -> (ss+1, kh*4 + e-2)
      const int nss = (e < 2) ? ss : ((ss + 1) & 15);
      const int nkk = (e < 2) ? (kk + 2) : (kh * 4 + (e - 2));
      const int fg = m4b + 4 * (nkk & 1) + mtg;
      const size_t base = ((size_t)(nss * 4 + (nkk >> 1)) * 32 + fg) * 512;
      #pragma unroll
      for (int mtp = 0; mtp < 2; ++mtp)
        va[e & 1][mtp] = *(const short8*)(vroot + base + mtp * 512);
    }
  }

  // ---- epilogue ----
  if (lane < 16) {
    #pragma unroll
    for (int nt = 0; nt < 4; ++nt) l_buf[w][16 * nt + lane] = l_r[nt];
  }
  BARRIER();
  if (kh == 1) {
    #pragma unroll
    for (int mtp = 0; mtp < 2; ++mtp)
      #pragma unroll
      for (int nt = 0; nt < 4; ++nt)
        *(f32x4*)&sm.Om[m8][mtp * 4 + nt][lane][0] = O[mtp][nt];
  }
  BARRIER();
  if (kh == 0) {
    const float gam = gamma_p[0];
    float inv_l[4];
    #pragma unroll
    for (int nt = 0; nt < 4; ++nt) {
      float s = 0.f;
      #pragma unroll
      for (int sl = 0; sl < 16; ++sl) s += l_buf[sl][16 * nt + cl];
      inv_l[nt] = 1.0f / s;
    }
    #pragma unroll
    for (int mtp = 0; mtp < 2; ++mtp) {
      #pragma unroll
      for (int nt = 0; nt < 4; ++nt) {
        const f32x4 om = *(const f32x4*)&sm.Om[m8][mtp * 4 + nt][lane][0];
        #pragma unroll
        for (int r = 0; r < 4; ++r) {
          const int ch = 32 * m8 + 16 * mtp + 4 * q4 + r;
          const int i  = i0 + 16 * nt + cl;
          const size_t idx = ((size_t)b * CC + ch) * LL + i;
          out[idx] = gam * (O[mtp][nt][r] + om[r]) * inv_l[nt] + x[idx];
        }
      }
    }
  }
}

extern "C" void kernel_launch(void* const* d_in, const int* in_sizes, int n_in,
                              void* d_out, int out_size, void* d_ws, size_t ws_size,
                              hipStream_t stream) {
  const float* x     = (const float*)d_in[0];
  const float* Wq    = (const float*)d_in[1];
  const float* bq    = (const float*)d_in[2];
  const float* Wk    = (const float*)d_in[3];
  const float* bk    = (const float*)d_in[4];
  const float* Wv    = (const float*)d_in[5];
  const float* bv    = (const float*)d_in[6];
  const float* gamma = (const float*)d_in[7];
  float* out = (float*)d_out;

  // ws: qT (1MB, log2e-scaled) | kT (1MB, sigma rows) | vf (8MB, fragment-linear)
  unsigned short* qT = (unsigned short*)d_ws;
  unsigned short* kT = qT + (size_t)BB * LL * DD;
  unsigned short* vf = kT + (size_t)BB * LL * DD;
  // wf (160KB) lives in d_out; consumed by qkv, then attn overwrites d_out
  unsigned short* wf = (unsigned short*)d_out;

  wprep_kernel<<<40, 256, 0, stream>>>(Wq, Wk, Wv, wf);
  qkv_kernel<<<512, 512, 0, stream>>>(x, wf, bq, bk, bv, qT, kT, vf);
  attn_kernel<<<256, 1024, 0, stream>>>(qT, kT, vf, x, gamma, out);
}

// Round 8
// 143.420 us; speedup vs baseline: 2.0859x; 1.1984x over previous
//
#include <hip/hip_runtime.h>
#include <math.h>

#define BB 4
#define CC 256
#define LL 4096
#define DD 32   // q/k channels
#define LOG2E 1.44269504088896f

typedef __attribute__((ext_vector_type(8))) short short8;   // 8 bf16 (4 VGPRs)
typedef __attribute__((ext_vector_type(4))) short short4v;
typedef __attribute__((ext_vector_type(4))) float f32x4;
typedef __attribute__((ext_vector_type(4))) unsigned int uint4v;
typedef __attribute__((ext_vector_type(2))) unsigned int uint2v;

// raw workgroup barrier: waits LDS ops only — global prefetches stay in flight
#define BARRIER() asm volatile("s_waitcnt lgkmcnt(0)\n\ts_barrier" ::: "memory")

__device__ inline unsigned short f2bf(float f) {
  union { float f; unsigned u; } v; v.f = f;
  unsigned r = v.u + 0x7fffu + ((v.u >> 16) & 1u);  // RNE
  return (unsigned short)(r >> 16);
}

__device__ inline float fast_exp2(float x) {
#if __has_builtin(__builtin_amdgcn_exp2f)
  return __builtin_amdgcn_exp2f(x);
#else
  return exp2f(x);
#endif
}

// natural key p -> kT storage row within its 32-key group (P C-layout == PV B-layout)
__device__ __host__ inline int sigma32(int p) {
  const int q4 = (p >> 3) & 3, u = p & 7;
  return 16 * (u >> 2) + 4 * q4 + (u & 3);
}

// ---------------- kernel 0: W -> bf16 MFMA-fragment-linear layout ----------------
// wf[ot(20)][ks(8)][lane(64)][8]; Wq rows pre-scaled by log2(e).
__global__ __launch_bounds__(256) void wprep_kernel(
    const float* __restrict__ Wq, const float* __restrict__ Wk, const float* __restrict__ Wv,
    unsigned short* __restrict__ wf)
{
  const int t = threadIdx.x;
  const int ot = blockIdx.x >> 1;           // 0..19
  const int rep = blockIdx.x & 1;
  const int lane = t & 63, cl = lane & 15, q4 = lane >> 4;
  const int ks = (t >> 6) + 4 * rep;        // 0..7
  const int o = ot * 16 + cl;
  const int c = ks * 32 + q4 * 8;
  const float* src = (o < 32) ? (Wq + o * CC) : (o < 64) ? (Wk + (o - 32) * CC)
                                              : (Wv + (o - 64) * CC);
  const float sc = (o < 32) ? LOG2E : 1.0f;
  unsigned short p[8];
  #pragma unroll
  for (int j = 0; j < 8; ++j) p[j] = f2bf(src[c + j] * sc);
  uint4v u;
  u.x = (unsigned)p[0] | ((unsigned)p[1] << 16);
  u.y = (unsigned)p[2] | ((unsigned)p[3] << 16);
  u.z = (unsigned)p[4] | ((unsigned)p[5] << 16);
  u.w = (unsigned)p[6] | ((unsigned)p[7] << 16);
  *(uint4v*)(wf + ((size_t)(ot * 8 + ks) * 64 + lane) * 8) = u;
}

// ---------------- kernel 1: fused transpose + QKV projection (R6-proven) ----------------
// grid 512 = (b, it 32-i tile) XCD-affine; 512 thr = 8 waves (wi 16-i, wo 5-ot).
__global__ __launch_bounds__(512, 4) void qkv_kernel(
    const float* __restrict__ x, const unsigned short* __restrict__ wf,
    const float* __restrict__ bq, const float* __restrict__ bk, const float* __restrict__ bv,
    unsigned short* __restrict__ qT, unsigned short* __restrict__ kT,
    unsigned short* __restrict__ vf)
{
  __shared__ union {
    float xl[32 * 261];                                   // [i][c] odd stride
    struct {
      unsigned short qk[32 * 72];                         // [i][o 0..63]
      __align__(16) unsigned short v[256 * 40];           // [ch][key 0..31] pad-40
    } ep;
  } sm;

  const int t = threadIdx.x;
  const int lane = t & 63, cl = lane & 15, q4 = lane >> 4;
  const int blk = blockIdx.x;
  const int b  = (blk & 7) >> 1;                          // XCD-batch affinity
  const int it = ((blk >> 3) << 1) + (blk & 1);           // 0..127
  const int i0 = it * 32;

  // ---- stage x: coalesced 128B rows -> LDS transposed ----
  {
    const int ln8 = t & 7;
    #pragma unroll
    for (int p = 0; p < 4; ++p) {
      const int c = (t >> 3) + 64 * p;
      const f32x4 v = *(const f32x4*)(x + ((size_t)(b * CC + c)) * LL + i0 + ln8 * 4);
      #pragma unroll
      for (int k = 0; k < 4; ++k) sm.xl[(ln8 * 4 + k) * 261 + c] = v[k];
    }
  }
  __syncthreads();

  // ---- GEMM: wave (wi,wo): 80 o-rows x 16 i x 256 c ----
  const int wi = (t >> 6) & 1, wo = t >> 7;
  const f32x4 zero = {0.f, 0.f, 0.f, 0.f};
  f32x4 acc[5];
  #pragma unroll
  for (int u = 0; u < 5; ++u) acc[u] = zero;

  for (int ks = 0; ks < 8; ++ks) {
    unsigned short p[8];
    #pragma unroll
    for (int j = 0; j < 8; ++j)
      p[j] = f2bf(sm.xl[(16 * wi + cl) * 261 + ks * 32 + q4 * 8 + j]);
    union { short8 s; uint4v u; } bfr;
    bfr.u.x = (unsigned)p[0] | ((unsigned)p[1] << 16);
    bfr.u.y = (unsigned)p[2] | ((unsigned)p[3] << 16);
    bfr.u.z = (unsigned)p[4] | ((unsigned)p[5] << 16);
    bfr.u.w = (unsigned)p[6] | ((unsigned)p[7] << 16);
    #pragma unroll
    for (int u = 0; u < 5; ++u) {
      const short8 a = *(const short8*)(wf + ((size_t)((wo * 5 + u) * 8 + ks) * 64 + lane) * 8);
      acc[u] = __builtin_amdgcn_mfma_f32_16x16x32_bf16(a, bfr.s, acc[u], 0, 0, 0);
    }
  }
  __syncthreads();   // xl dead; alias as ep

  // ---- stage outputs ----
  #pragma unroll
  for (int u = 0; u < 5; ++u) {
    const int g = wo * 5 + u;
    if (g < 4) {     // q (g<2) / k
      short4v pk;
      #pragma unroll
      for (int r = 0; r < 4; ++r) {
        const int o = 16 * g + 4 * q4 + r;
        const float v = acc[u][r] + ((o < 32) ? bq[o] * LOG2E : bk[o - 32]);
        pk[r] = (short)f2bf(v);
      }
      *(short4v*)&sm.ep.qk[(16 * wi + cl) * 72 + 16 * g + 4 * q4] = pk;
    } else {
      #pragma unroll
      for (int r = 0; r < 4; ++r) {
        const int ch = 16 * (g - 4) + 4 * q4 + r;
        sm.ep.v[ch * 40 + 16 * wi + cl] = f2bf(acc[u][r] + bv[ch]);
      }
    }
  }
  __syncthreads();

  // ---- coalesced stores ----
  if (t < 64) {
    const int i = t >> 1, which = t & 1;
    const int gi = i0 + i;
    const unsigned short* srcp = &sm.ep.qk[i * 72 + which * 32];
    uint4v d0 = *(const uint4v*)(srcp + 0);
    uint4v d1 = *(const uint4v*)(srcp + 8);
    uint4v d2 = *(const uint4v*)(srcp + 16);
    uint4v d3 = *(const uint4v*)(srcp + 24);
    unsigned short* dst;
    if (which == 0) {
      dst = qT + ((size_t)b * LL + gi) * DD;
    } else {
      const int row = (gi & ~31) + sigma32(gi & 31);
      dst = kT + ((size_t)b * LL + row) * DD;
    }
    *(uint4v*)dst = d0; *(uint4v*)(dst + 8) = d1;
    *(uint4v*)(dst + 16) = d2; *(uint4v*)(dst + 24) = d3;
  }
  // vf: this block covers kk = it&1 of jt = it>>1: 16 frags x 1KB
  const int kk = it & 1, jt = it >> 1;
  #pragma unroll
  for (int rep = 0; rep < 2; ++rep) {
    const int slot = t + 512 * rep;
    const int fl = slot >> 6, l2 = slot & 63;
    const int cl2 = l2 & 15, q42 = l2 >> 4;
    const int m4 = fl >> 2, mt = fl & 3;
    const int fg = 8 * m4 + 4 * kk + mt;
    const int ch = 64 * m4 + 16 * mt + cl2;
    const uint4v d = *(const uint4v*)&sm.ep.v[ch * 40 + q42 * 8];
    *(uint4v*)(vf + (((size_t)(b * 64 + jt)) * 32 + fg) * 512 + l2 * 8) = d;
  }
}

// ---------------- kernel 2: flash attention, LDS-shared P (conflict-free layout) --------
// grid 256 = (b, it 64-q tile); 1024 thr = 16 waves.
// Superstep = 256 keys. Phase A: wave w computes S/exp for 16-key slice w -> P LDS (dbuf).
// Phase B: wave (m8=w>>1: 32ch, kh=w&1: 128-key half) PV from LDS P + 1KB va frags.
// P stored as [kk][nt][half][lane][4]: 8B/lane stride -> conflict-free b64 writes AND reads.
__global__ __launch_bounds__(1024, 4) void attn_kernel(
    const unsigned short* __restrict__ qT, const unsigned short* __restrict__ kT,
    const unsigned short* __restrict__ vf, const float* __restrict__ x,
    const float* __restrict__ gamma_p, float* __restrict__ out)
{
  __shared__ union {
    unsigned short P[2][8][4][2][64][4];  // [buf][kk][nt][half][lane][j]  64 KB
    float Om[8][8][64][4];                // epilogue merge                 64 KB
  } sm;
  __shared__ float l_buf[16][64];

  const int t = threadIdx.x;
  const int w = t >> 6, lane = t & 63, cl = lane & 15, q4 = lane >> 4;
  const int m8 = w >> 1, kh = w & 1;
  const int blk = blockIdx.x;
  const int b  = (blk & 7) >> 1;
  const int it = ((blk >> 3) << 1) + (blk & 1);           // 0..63
  const int i0 = it * 64;

  // persistent Q B-frags (one per 16-query tile)
  short8 qa[4];
  #pragma unroll
  for (int nt = 0; nt < 4; ++nt)
    qa[nt] = *(const short8*)(qT + ((size_t)b * LL + i0 + 16 * nt + cl) * DD + q4 * 8);

  const f32x4 zero = {0.f, 0.f, 0.f, 0.f};
  f32x4 O[2][4];
  #pragma unroll
  for (int mtp = 0; mtp < 2; ++mtp)
    #pragma unroll
    for (int nt = 0; nt < 4; ++nt) O[mtp][nt] = zero;
  float l_r[4] = {0.f, 0.f, 0.f, 0.f};

  const unsigned short* kbase = kT + ((size_t)b * LL + 16 * w + cl) * DD + q4 * 8;
  const unsigned short* vroot = vf + ((size_t)(b * 64)) * 32 * 512 + lane * 8;
  // va address for (ss, e): kk = kh*4+e; jt = ss*4 + (kk>>1); fg = 8*(m8>>1) + 4*(kk&1) + 2*(m8&1)+mtp
  const int mtg = 2 * (m8 & 1), m4b = 8 * (m8 >> 1);

  short8 kb = *(const short8*)kbase;
  short8 va[2][2];
  #pragma unroll
  for (int e = 0; e < 2; ++e) {
    const int kk = kh * 4 + e;
    const int fg = m4b + 4 * (kk & 1) + mtg;
    #pragma unroll
    for (int mtp = 0; mtp < 2; ++mtp)
      va[e][mtp] = *(const short8*)(vroot + ((size_t)((kk >> 1) * 32) + fg + mtp) * 512);
  }

  for (int ss = 0; ss < 16; ++ss) {
    const int buf = ss & 1;

    // ---- phase A: S for this wave's 16-key slice ----
    f32x4 s[4];
    #pragma unroll
    for (int nt = 0; nt < 4; ++nt)
      s[nt] = __builtin_amdgcn_mfma_f32_16x16x32_bf16(kb, qa[nt], zero, 0, 0, 0);
    // prefetch next superstep's kb (in flight across barrier)
    kb = *(const short8*)(kbase + (size_t)((ss + 1) & 15) * 256 * DD);

    #pragma unroll
    for (int nt = 0; nt < 4; ++nt) {
      const float e0 = fast_exp2(s[nt][0]);
      const float e1 = fast_exp2(s[nt][1]);
      const float e2 = fast_exp2(s[nt][2]);
      const float e3 = fast_exp2(s[nt][3]);
      uint2v uv;
      uv.x = __builtin_amdgcn_perm(__float_as_uint(e1), __float_as_uint(e0), 0x07060302);
      uv.y = __builtin_amdgcn_perm(__float_as_uint(e3), __float_as_uint(e2), 0x07060302);
      *(uint2v*)&sm.P[buf][w >> 1][nt][w & 1][lane][0] = uv;   // 8B/lane: conflict-free
      float sum = (e0 + e1) + (e2 + e3);
      sum += __shfl_xor(sum, 16);
      sum += __shfl_xor(sum, 32);
      l_r[nt] += sum;
    }
    BARRIER();

    // ---- phase B: PV over this wave's 128-key half ----
    #pragma unroll
    for (int e = 0; e < 4; ++e) {
      const int kk = kh * 4 + e;
      short8 pb[4];
      #pragma unroll
      for (int nt = 0; nt < 4; ++nt) {
        union { short8 s8; uint2v h[2]; } pbu;
        pbu.h[0] = *(const uint2v*)&sm.P[buf][kk][nt][0][lane][0];  // b64, 8B stride
        pbu.h[1] = *(const uint2v*)&sm.P[buf][kk][nt][1][lane][0];
        pb[nt] = pbu.s8;
      }
      #pragma unroll
      for (int nt = 0; nt < 4; ++nt) {
        O[0][nt] = __builtin_amdgcn_mfma_f32_16x16x32_bf16(va[e & 1][0], pb[nt], O[0][nt], 0, 0, 0);
        O[1][nt] = __builtin_amdgcn_mfma_f32_16x16x32_bf16(va[e & 1][1], pb[nt], O[1][nt], 0, 0, 0);
      }
      // refill the consumed slot: e<2 -> (ss, kk+2); else -> (ss+1, kh*4 + e-2)
      const int nss = (e < 2) ? ss : ((ss + 1) & 15);
      const int nkk = (e < 2) ? (kk + 2) : (kh * 4 + (e - 2));
      const int fg = m4b + 4 * (nkk & 1) + mtg;
      const size_t base = ((size_t)(nss * 4 + (nkk >> 1)) * 32 + fg) * 512;
      #pragma unroll
      for (int mtp = 0; mtp < 2; ++mtp)
        va[e & 1][mtp] = *(const short8*)(vroot + base + mtp * 512);
    }
  }

  // ---- epilogue ----
  if (lane < 16) {
    #pragma unroll
    for (int nt = 0; nt < 4; ++nt) l_buf[w][16 * nt + lane] = l_r[nt];
  }
  BARRIER();
  if (kh == 1) {
    #pragma unroll
    for (int mtp = 0; mtp < 2; ++mtp)
      #pragma unroll
      for (int nt = 0; nt < 4; ++nt)
        *(f32x4*)&sm.Om[m8][mtp * 4 + nt][lane][0] = O[mtp][nt];
  }
  BARRIER();
  if (kh == 0) {
    const float gam = gamma_p[0];
    float inv_l[4];
    #pragma unroll
    for (int nt = 0; nt < 4; ++nt) {
      float s = 0.f;
      #pragma unroll
      for (int sl = 0; sl < 16; ++sl) s += l_buf[sl][16 * nt + cl];
      inv_l[nt] = 1.0f / s;
    }
    #pragma unroll
    for (int mtp = 0; mtp < 2; ++mtp) {
      #pragma unroll
      for (int nt = 0; nt < 4; ++nt) {
        const f32x4 om = *(const f32x4*)&sm.Om[m8][mtp * 4 + nt][lane][0];
        #pragma unroll
        for (int r = 0; r < 4; ++r) {
          const int ch = 32 * m8 + 16 * mtp + 4 * q4 + r;
          const int i  = i0 + 16 * nt + cl;
          const size_t idx = ((size_t)b * CC + ch) * LL + i;
          out[idx] = gam * (O[mtp][nt][r] + om[r]) * inv_l[nt] + x[idx];
        }
      }
    }
  }
}

extern "C" void kernel_launch(void* const* d_in, const int* in_sizes, int n_in,
                              void* d_out, int out_size, void* d_ws, size_t ws_size,
                              hipStream_t stream) {
  const float* x     = (const float*)d_in[0];
  const float* Wq    = (const float*)d_in[1];
  const float* bq    = (const float*)d_in[2];
  const float* Wk    = (const float*)d_in[3];
  const float* bk    = (const float*)d_in[4];
  const float* Wv    = (const float*)d_in[5];
  const float* bv    = (const float*)d_in[6];
  const float* gamma = (const float*)d_in[7];
  float* out = (float*)d_out;

  // ws: qT (1MB, log2e-scaled) | kT (1MB, sigma rows) | vf (8MB, fragment-linear)
  unsigned short* qT = (unsigned short*)d_ws;
  unsigned short* kT = qT + (size_t)BB * LL * DD;
  unsigned short* vf = kT + (size_t)BB * LL * DD;
  // wf (160KB) lives in d_out; consumed by qkv, then attn overwrites d_out
  unsigned short* wf = (unsigned short*)d_out;

  wprep_kernel<<<40, 256, 0, stream>>>(Wq, Wk, Wv, wf);
  qkv_kernel<<<512, 512, 0, stream>>>(x, wf, bq, bk, bv, qT, kT, vf);
  attn_kernel<<<256, 1024, 0, stream>>>(qT, kT, vf, x, gamma, out);
}

// Round 9
// 141.476 us; speedup vs baseline: 2.1146x; 1.0137x over previous
//
#include <hip/hip_runtime.h>
#include <math.h>

#define BB 4
#define CC 256
#define LL 4096
#define DD 32   // q/k channels
#define LOG2E 1.44269504088896f

typedef __attribute__((ext_vector_type(8))) short short8;   // 8 bf16 (4 VGPRs)
typedef __attribute__((ext_vector_type(4))) short short4v;
typedef __attribute__((ext_vector_type(4))) float f32x4;
typedef __attribute__((ext_vector_type(4))) unsigned int uint4v;
typedef __attribute__((ext_vector_type(2))) unsigned int uint2v;

// raw workgroup barrier: waits LDS ops only — global prefetches stay in flight
#define BARRIER() asm volatile("s_waitcnt lgkmcnt(0)\n\ts_barrier" ::: "memory")

__device__ inline unsigned short f2bf(float f) {
  union { float f; unsigned u; } v; v.f = f;
  unsigned r = v.u + 0x7fffu + ((v.u >> 16) & 1u);  // RNE
  return (unsigned short)(r >> 16);
}

__device__ inline float fast_exp2(float x) {
#if __has_builtin(__builtin_amdgcn_exp2f)
  return __builtin_amdgcn_exp2f(x);
#else
  return exp2f(x);
#endif
}

// natural key p -> kT storage row within its 32-key group (P C-layout == PV B-layout)
__device__ __host__ inline int sigma32(int p) {
  const int q4 = (p >> 3) & 3, u = p & 7;
  return 16 * (u >> 2) + 4 * q4 + (u & 3);
}

// ---------------- kernel 0: W -> bf16 MFMA-fragment-linear layout ----------------
// wf[ot(20)][ks(8)][lane(64)][8]; Wq rows pre-scaled by log2(e).
__global__ __launch_bounds__(256) void wprep_kernel(
    const float* __restrict__ Wq, const float* __restrict__ Wk, const float* __restrict__ Wv,
    unsigned short* __restrict__ wf)
{
  const int t = threadIdx.x;
  const int ot = blockIdx.x >> 1;           // 0..19
  const int rep = blockIdx.x & 1;
  const int lane = t & 63, cl = lane & 15, q4 = lane >> 4;
  const int ks = (t >> 6) + 4 * rep;        // 0..7
  const int o = ot * 16 + cl;
  const int c = ks * 32 + q4 * 8;
  const float* src = (o < 32) ? (Wq + o * CC) : (o < 64) ? (Wk + (o - 32) * CC)
                                              : (Wv + (o - 64) * CC);
  const float sc = (o < 32) ? LOG2E : 1.0f;
  unsigned short p[8];
  #pragma unroll
  for (int j = 0; j < 8; ++j) p[j] = f2bf(src[c + j] * sc);
  uint4v u;
  u.x = (unsigned)p[0] | ((unsigned)p[1] << 16);
  u.y = (unsigned)p[2] | ((unsigned)p[3] << 16);
  u.z = (unsigned)p[4] | ((unsigned)p[5] << 16);
  u.w = (unsigned)p[6] | ((unsigned)p[7] << 16);
  *(uint4v*)(wf + ((size_t)(ot * 8 + ks) * 64 + lane) * 8) = u;
}

// ---------------- kernel 1: fused transpose + QKV projection (R6-proven) ----------------
// grid 512 = (b, it 32-i tile) XCD-affine; 512 thr = 8 waves (wi 16-i, wo 5-ot).
__global__ __launch_bounds__(512, 4) void qkv_kernel(
    const float* __restrict__ x, const unsigned short* __restrict__ wf,
    const float* __restrict__ bq, const float* __restrict__ bk, const float* __restrict__ bv,
    unsigned short* __restrict__ qT, unsigned short* __restrict__ kT,
    unsigned short* __restrict__ vf)
{
  __shared__ union {
    float xl[32 * 261];                                   // [i][c] odd stride
    struct {
      unsigned short qk[32 * 72];                         // [i][o 0..63]
      __align__(16) unsigned short v[256 * 40];           // [ch][key 0..31] pad-40
    } ep;
  } sm;

  const int t = threadIdx.x;
  const int lane = t & 63, cl = lane & 15, q4 = lane >> 4;
  const int blk = blockIdx.x;
  const int b  = (blk & 7) >> 1;                          // XCD-batch affinity
  const int it = ((blk >> 3) << 1) + (blk & 1);           // 0..127
  const int i0 = it * 32;

  // ---- stage x: coalesced 128B rows -> LDS transposed ----
  {
    const int ln8 = t & 7;
    #pragma unroll
    for (int p = 0; p < 4; ++p) {
      const int c = (t >> 3) + 64 * p;
      const f32x4 v = *(const f32x4*)(x + ((size_t)(b * CC + c)) * LL + i0 + ln8 * 4);
      #pragma unroll
      for (int k = 0; k < 4; ++k) sm.xl[(ln8 * 4 + k) * 261 + c] = v[k];
    }
  }
  __syncthreads();

  // ---- GEMM: wave (wi,wo): 80 o-rows x 16 i x 256 c ----
  const int wi = (t >> 6) & 1, wo = t >> 7;
  const f32x4 zero = {0.f, 0.f, 0.f, 0.f};
  f32x4 acc[5];
  #pragma unroll
  for (int u = 0; u < 5; ++u) acc[u] = zero;

  for (int ks = 0; ks < 8; ++ks) {
    unsigned short p[8];
    #pragma unroll
    for (int j = 0; j < 8; ++j)
      p[j] = f2bf(sm.xl[(16 * wi + cl) * 261 + ks * 32 + q4 * 8 + j]);
    union { short8 s; uint4v u; } bfr;
    bfr.u.x = (unsigned)p[0] | ((unsigned)p[1] << 16);
    bfr.u.y = (unsigned)p[2] | ((unsigned)p[3] << 16);
    bfr.u.z = (unsigned)p[4] | ((unsigned)p[5] << 16);
    bfr.u.w = (unsigned)p[6] | ((unsigned)p[7] << 16);
    #pragma unroll
    for (int u = 0; u < 5; ++u) {
      const short8 a = *(const short8*)(wf + ((size_t)((wo * 5 + u) * 8 + ks) * 64 + lane) * 8);
      acc[u] = __builtin_amdgcn_mfma_f32_16x16x32_bf16(a, bfr.s, acc[u], 0, 0, 0);
    }
  }
  __syncthreads();   // xl dead; alias as ep

  // ---- stage outputs ----
  #pragma unroll
  for (int u = 0; u < 5; ++u) {
    const int g = wo * 5 + u;
    if (g < 4) {     // q (g<2) / k
      short4v pk;
      #pragma unroll
      for (int r = 0; r < 4; ++r) {
        const int o = 16 * g + 4 * q4 + r;
        const float v = acc[u][r] + ((o < 32) ? bq[o] * LOG2E : bk[o - 32]);
        pk[r] = (short)f2bf(v);
      }
      *(short4v*)&sm.ep.qk[(16 * wi + cl) * 72 + 16 * g + 4 * q4] = pk;
    } else {
      #pragma unroll
      for (int r = 0; r < 4; ++r) {
        const int ch = 16 * (g - 4) + 4 * q4 + r;
        sm.ep.v[ch * 40 + 16 * wi + cl] = f2bf(acc[u][r] + bv[ch]);
      }
    }
  }
  __syncthreads();

  // ---- coalesced stores ----
  if (t < 64) {
    const int i = t >> 1, which = t & 1;
    const int gi = i0 + i;
    const unsigned short* srcp = &sm.ep.qk[i * 72 + which * 32];
    uint4v d0 = *(const uint4v*)(srcp + 0);
    uint4v d1 = *(const uint4v*)(srcp + 8);
    uint4v d2 = *(const uint4v*)(srcp + 16);
    uint4v d3 = *(const uint4v*)(srcp + 24);
    unsigned short* dst;
    if (which == 0) {
      dst = qT + ((size_t)b * LL + gi) * DD;
    } else {
      const int row = (gi & ~31) + sigma32(gi & 31);
      dst = kT + ((size_t)b * LL + row) * DD;
    }
    *(uint4v*)dst = d0; *(uint4v*)(dst + 8) = d1;
    *(uint4v*)(dst + 16) = d2; *(uint4v*)(dst + 24) = d3;
  }
  // vf: this block covers kk = it&1 of jt = it>>1: 16 frags x 1KB
  const int kk = it & 1, jt = it >> 1;
  #pragma unroll
  for (int rep = 0; rep < 2; ++rep) {
    const int slot = t + 512 * rep;
    const int fl = slot >> 6, l2 = slot & 63;
    const int cl2 = l2 & 15, q42 = l2 >> 4;
    const int m4 = fl >> 2, mt = fl & 3;
    const int fg = 8 * m4 + 4 * kk + mt;
    const int ch = 64 * m4 + 16 * mt + cl2;
    const uint4v d = *(const uint4v*)&sm.ep.v[ch * 40 + q42 * 8];
    *(uint4v*)(vf + (((size_t)(b * 64 + jt)) * 32 + fg) * 512 + l2 * 8) = d;
  }
}

// ---------------- kernel 2: flash attention, 32-q blocks, 2 blocks/CU ----------------
// grid 512 = (b, it 32-q tile); 512 thr = 8 waves.
// Superstep = 256 keys. Phase A: wave w computes S/exp for its 32-key group kk=w
// (2 kb frags) -> P LDS (dbuf, conflict-free 8B/lane layout).
// Phase B: wave (m4 = w&3: 64 ch, kh = w>>2: 128-key half) PV: 4 kk x 4 mt x 2 nt MFMAs.
// l: per-lane partials only in-loop (no cross-lane ops); reduced once in epilogue.
__global__ __launch_bounds__(512, 4) void attn_kernel(
    const unsigned short* __restrict__ qT, const unsigned short* __restrict__ kT,
    const unsigned short* __restrict__ vf, const float* __restrict__ x,
    const float* __restrict__ gamma_p, float* __restrict__ out)
{
  __shared__ union {
    unsigned short P[2][8][2][2][64][4];  // [buf][kk][nt][half][lane][j]  32 KB
    float Om[4][8][64][4];                // [m4][mt*2+nt][lane][r]        32 KB
  } sm;
  __shared__ float l_lds[8][2][64];       // [wave][nt][lane] partial l

  const int t = threadIdx.x;
  const int w = t >> 6, lane = t & 63, cl = lane & 15, q4 = lane >> 4;
  const int m4 = w & 3, kh = w >> 2;
  const int blk = blockIdx.x;
  const int b  = (blk & 7) >> 1;                          // matches qkv affinity
  const int it = ((blk >> 3) << 1) + (blk & 1);           // 0..127
  const int i0 = it * 32;

  // persistent Q B-frags (2 16-query tiles)
  short8 qa[2];
  #pragma unroll
  for (int nt = 0; nt < 2; ++nt)
    qa[nt] = *(const short8*)(qT + ((size_t)b * LL + i0 + 16 * nt + cl) * DD + q4 * 8);

  const f32x4 zero = {0.f, 0.f, 0.f, 0.f};
  f32x4 O[4][2];                          // [mt][nt]: ch 64*m4+16*mt, q 16*nt
  #pragma unroll
  for (int mt = 0; mt < 4; ++mt)
    #pragma unroll
    for (int nt = 0; nt < 2; ++nt) O[mt][nt] = zero;
  float l_r[2] = {0.f, 0.f};

  // phase A source: kT rows [ss*256 + 32*w + 16*h), sigma-permuted
  const unsigned short* kbase = kT + ((size_t)b * LL + 32 * w + cl) * DD + q4 * 8;
  // phase B source: frag f = (ss*4 + (kk>>1))*32 + 8*m4 + 4*(kk&1) + mt
  const unsigned short* vroot = vf + ((size_t)(b * 64)) * 32 * 512 + lane * 8;

  short8 kb[2];
  #pragma unroll
  for (int h = 0; h < 2; ++h)
    kb[h] = *(const short8*)(kbase + (size_t)(16 * h) * DD);

  short8 va[2][4];                        // [slot e&1][mt]
  #pragma unroll
  for (int e = 0; e < 2; ++e) {
    const int kk = 4 * kh + e;
    const size_t base = ((size_t)((kk >> 1) * 32) + 8 * m4 + 4 * (kk & 1)) * 512;
    #pragma unroll
    for (int mt = 0; mt < 4; ++mt)
      va[e][mt] = *(const short8*)(vroot + base + mt * 512);
  }

  for (int ss = 0; ss < 16; ++ss) {
    const int buf = ss & 1;

    // ---- phase A: S/exp for this wave's 32-key group (kk = w) ----
    f32x4 s[2][2];                        // [h][nt]
    #pragma unroll
    for (int h = 0; h < 2; ++h)
      #pragma unroll
      for (int nt = 0; nt < 2; ++nt)
        s[h][nt] = __builtin_amdgcn_mfma_f32_16x16x32_bf16(kb[h], qa[nt], zero, 0, 0, 0);
    // prefetch next superstep's kb (in flight across barrier)
    #pragma unroll
    for (int h = 0; h < 2; ++h)
      kb[h] = *(const short8*)(kbase + (size_t)(((ss + 1) & 15) * 256 + 16 * h) * DD);

    #pragma unroll
    for (int h = 0; h < 2; ++h)
      #pragma unroll
      for (int nt = 0; nt < 2; ++nt) {
        const float e0 = fast_exp2(s[h][nt][0]);
        const float e1 = fast_exp2(s[h][nt][1]);
        const float e2 = fast_exp2(s[h][nt][2]);
        const float e3 = fast_exp2(s[h][nt][3]);
        uint2v uv;
        uv.x = __builtin_amdgcn_perm(__float_as_uint(e1), __float_as_uint(e0), 0x07060302);
        uv.y = __builtin_amdgcn_perm(__float_as_uint(e3), __float_as_uint(e2), 0x07060302);
        *(uint2v*)&sm.P[buf][w][nt][h][lane][0] = uv;   // 8B/lane: conflict-free
        l_r[nt] += (e0 + e1) + (e2 + e3);               // per-lane partial, no shuffles
      }
    BARRIER();

    // ---- phase B: PV for ch 64*m4 over kk = 4*kh .. 4*kh+3 ----
    #pragma unroll
    for (int e = 0; e < 4; ++e) {
      const int kk = 4 * kh + e;
      short8 pb[2];
      #pragma unroll
      for (int nt = 0; nt < 2; ++nt) {
        union { short8 s8; uint2v h[2]; } pbu;
        pbu.h[0] = *(const uint2v*)&sm.P[buf][kk][nt][0][lane][0];  // b64, conflict-free
        pbu.h[1] = *(const uint2v*)&sm.P[buf][kk][nt][1][lane][0];
        pb[nt] = pbu.s8;
      }
      #pragma unroll
      for (int mt = 0; mt < 4; ++mt)
        #pragma unroll
        for (int nt = 0; nt < 2; ++nt)
          O[mt][nt] = __builtin_amdgcn_mfma_f32_16x16x32_bf16(va[e & 1][mt], pb[nt],
                                                              O[mt][nt], 0, 0, 0);
      // refill consumed slot: e<2 -> (ss, kk+2); else -> (ss+1, 4kh + e-2)
      const int nss = (e < 2) ? ss : ((ss + 1) & 15);
      const int nkk = (e < 2) ? (kk + 2) : (4 * kh + (e - 2));
      const size_t base = ((size_t)(nss * 4 + (nkk >> 1)) * 32 + 8 * m4 + 4 * (nkk & 1)) * 512;
      #pragma unroll
      for (int mt = 0; mt < 4; ++mt)
        va[e & 1][mt] = *(const short8*)(vroot + base + mt * 512);
    }
  }

  // ---- epilogue ----
  l_lds[w][0][lane] = l_r[0];
  l_lds[w][1][lane] = l_r[1];
  BARRIER();   // all P reads done (Om may overwrite) + l_lds visible
  if (kh == 1) {
    #pragma unroll
    for (int mt = 0; mt < 4; ++mt)
      #pragma unroll
      for (int nt = 0; nt < 2; ++nt)
        *(f32x4*)&sm.Om[m4][mt * 2 + nt][lane][0] = O[mt][nt];
  }
  BARRIER();
  if (kh == 0) {
    const float gam = gamma_p[0];
    float inv_l[2];
    #pragma unroll
    for (int nt = 0; nt < 2; ++nt) {
      float s = 0.f;
      #pragma unroll
      for (int sl = 0; sl < 8; ++sl)
        #pragma unroll
        for (int g = 0; g < 4; ++g)
          s += l_lds[sl][nt][g * 16 + cl];
      inv_l[nt] = 1.0f / s;
    }
    #pragma unroll
    for (int mt = 0; mt < 4; ++mt) {
      #pragma unroll
      for (int nt = 0; nt < 2; ++nt) {
        const f32x4 om = *(const f32x4*)&sm.Om[m4][mt * 2 + nt][lane][0];
        #pragma unroll
        for (int r = 0; r < 4; ++r) {
          const int ch = 64 * m4 + 16 * mt + 4 * q4 + r;
          const int i  = i0 + 16 * nt + cl;
          const size_t idx = ((size_t)b * CC + ch) * LL + i;
          out[idx] = gam * (O[mt][nt][r] + om[r]) * inv_l[nt] + x[idx];
        }
      }
    }
  }
}

extern "C" void kernel_launch(void* const* d_in, const int* in_sizes, int n_in,
                              void* d_out, int out_size, void* d_ws, size_t ws_size,
                              hipStream_t stream) {
  const float* x     = (const float*)d_in[0];
  const float* Wq    = (const float*)d_in[1];
  const float* bq    = (const float*)d_in[2];
  const float* Wk    = (const float*)d_in[3];
  const float* bk    = (const float*)d_in[4];
  const float* Wv    = (const float*)d_in[5];
  const float* bv    = (const float*)d_in[6];
  const float* gamma = (const float*)d_in[7];
  float* out = (float*)d_out;

  // ws: qT (1MB, log2e-scaled) | kT (1MB, sigma rows) | vf (8MB, fragment-linear)
  unsigned short* qT = (unsigned short*)d_ws;
  unsigned short* kT = qT + (size_t)BB * LL * DD;
  unsigned short* vf = kT + (size_t)BB * LL * DD;
  // wf (160KB) lives in d_out; consumed by qkv, then attn overwrites d_out
  unsigned short* wf = (unsigned short*)d_out;

  wprep_kernel<<<40, 256, 0, stream>>>(Wq, Wk, Wv, wf);
  qkv_kernel<<<512, 512, 0, stream>>>(x, wf, bq, bk, bv, qT, kT, vf);
  attn_kernel<<<512, 512, 0, stream>>>(qT, kT, vf, x, gamma, out);
}